// Round 3
// baseline (561.533 us; speedup 1.0000x reference)
//
#include <hip/hip_runtime.h>
#include <hip/hip_bf16.h>
#include <math.h>

#define En   8
#define Bn   4096
#define Ln   512
#define K1n  1024   // 2L
#define H1n  1024
#define H2n  512
#define Cn   40

// ---------------------------------------------------------------------------
// Routing: histogram labels, exclusive scan, scatter sample ids -> perm.
// Single block. meta[0..8] = expert offsets.
// ---------------------------------------------------------------------------
__global__ __launch_bounds__(1024) void route_kernel(
    const int* __restrict__ label, int* __restrict__ meta, int* __restrict__ perm)
{
    __shared__ int cnt[En];
    __shared__ int off[En + 1];
    const int tid = threadIdx.x;
    if (tid < En) cnt[tid] = 0;
    __syncthreads();
    for (int b = tid; b < Bn; b += 1024) atomicAdd(&cnt[label[b]], 1);
    __syncthreads();
    if (tid == 0) {
        int run = 0;
        for (int e = 0; e < En; e++) { off[e] = run; run += cnt[e]; }
        off[En] = run;
    }
    __syncthreads();
    if (tid < En) cnt[tid] = off[tid];   // cursors
    __syncthreads();
    for (int b = tid; b < Bn; b += 1024) {
        int e = label[b];
        int pos = atomicAdd(&cnt[e], 1);
        perm[pos] = b;
    }
    if (tid <= En) meta[tid] = off[tid];
}

// ---------------------------------------------------------------------------
// Grouped GEMM + bias + ELU.  out[r, j] = elu( sum_k A[r,k] * W[e,k,j] + b[e,j] )
// Rows are in sorted (per-expert-contiguous) order. blockIdx.x maps to
// (expert, row-tile); blockIdx.y to a 128-col tile.
// GATHER=true: A row r = concat(x_p, x_s) of sample perm[r] (layer 1).
// GATHER=false: A = contiguous sorted matrix (layer 2).
// ---------------------------------------------------------------------------
template <int K, int N, bool GATHER>
__global__ __launch_bounds__(256) void gemm_elu(
    const float* __restrict__ Ain,
    const float* __restrict__ xp, const float* __restrict__ xs,
    const float* __restrict__ W, const float* __restrict__ bias,
    const int* __restrict__ meta, const int* __restrict__ perm,
    float* __restrict__ out)
{
    constexpr int TM = 64, TN = 128, TK = 32;
    __shared__ float As[TK][TM + 1];   // +1 pad: conflict-free column writes
    __shared__ float Bs[TK][TN];
    __shared__ int s_off[En + 1];

    const int tid = threadIdx.x;
    if (tid <= En) s_off[tid] = meta[tid];
    __syncthreads();

    // map blockIdx.x -> (expert, row0, rows)
    int expert = -1, row0 = 0, rows = 0, acc_t = 0;
    const int bx = blockIdx.x;
    for (int e = 0; e < En; e++) {
        int c = s_off[e + 1] - s_off[e];
        int t = (c + TM - 1) / TM;
        if (expert < 0 && bx < acc_t + t) {
            expert = e;
            row0 = s_off[e] + (bx - acc_t) * TM;
            rows = min(TM, s_off[e + 1] - row0);
        }
        acc_t += t;
    }
    if (expert < 0) return;

    const int j0 = blockIdx.y * TN;
    const float* Wexp = W + (size_t)expert * K * N;

    const int tx = tid & 15, ty = tid >> 4;
    const int m0 = ty * 4;        // 4 rows per thread
    const int jj0 = tx * 8;       // 8 cols per thread

    // hoist gathered sample ids (A-load pattern: kk = tid&31, m = (tid>>5)+s*8)
    const int lm = tid >> 5;      // 0..7
    int smp[8];
    const float* arow[8];
    #pragma unroll
    for (int s = 0; s < 8; s++) {
        int m = lm + s * 8;
        if (GATHER) {
            smp[s] = (m < rows) ? perm[row0 + m] : -1;
        } else {
            arow[s] = (m < rows) ? (Ain + (size_t)(row0 + m) * K) : nullptr;
        }
    }

    float acc[4][8];
    #pragma unroll
    for (int i = 0; i < 4; i++)
        #pragma unroll
        for (int j = 0; j < 8; j++) acc[i][j] = 0.f;

    for (int k0 = 0; k0 < K; k0 += TK) {
        // stage A tile: 64 rows x 32 k
        const int kk = tid & 31;
        #pragma unroll
        for (int s = 0; s < 8; s++) {
            int m = lm + s * 8;
            float v = 0.f;
            if (GATHER) {
                if (smp[s] >= 0) {
                    int ig = k0 + kk;
                    v = (ig < Ln) ? xp[(size_t)smp[s] * Ln + ig]
                                  : xs[(size_t)smp[s] * Ln + (ig - Ln)];
                }
            } else {
                if (arow[s]) v = arow[s][k0 + kk];
            }
            As[kk][m] = v;
        }
        // stage B tile: 32 k x 128 cols (float4 coalesced)
        #pragma unroll
        for (int s = 0; s < 4; s++) {
            int idx = tid + s * 256;
            int bk = idx >> 5;          // 0..31
            int j4 = idx & 31;          // 0..31 float4 within row
            float4 v = *(const float4*)&Wexp[(size_t)(k0 + bk) * N + j0 + j4 * 4];
            *(float4*)&Bs[bk][j4 * 4] = v;
        }
        __syncthreads();

        #pragma unroll
        for (int k = 0; k < TK; k++) {
            float aa[4];
            #pragma unroll
            for (int i = 0; i < 4; i++) aa[i] = As[k][m0 + i];
            float4 bv0 = *(const float4*)&Bs[k][jj0];
            float4 bv1 = *(const float4*)&Bs[k][jj0 + 4];
            float bb[8] = {bv0.x, bv0.y, bv0.z, bv0.w, bv1.x, bv1.y, bv1.z, bv1.w};
            #pragma unroll
            for (int i = 0; i < 4; i++)
                #pragma unroll
                for (int j = 0; j < 8; j++)
                    acc[i][j] = fmaf(aa[i], bb[j], acc[i][j]);
        }
        __syncthreads();
    }

    // epilogue: bias + ELU
    #pragma unroll
    for (int i = 0; i < 4; i++) {
        int m = m0 + i;
        if (m < rows) {
            float* orow = &out[(size_t)(row0 + m) * N + j0 + jj0];
            #pragma unroll
            for (int j = 0; j < 8; j++) {
                float v = acc[i][j] + bias[expert * N + j0 + jj0 + j];
                v = (v > 0.f) ? v : (expf(v) - 1.f);
                orow[j] = v;
            }
        }
    }
}

// ---------------------------------------------------------------------------
// Layer 3: [rows,512] x [512,40] + b3, scatter to out[perm[r]] as FP32.
// TM=256 rows per block; thread = 4 rows x 10 cols.
// ---------------------------------------------------------------------------
__global__ __launch_bounds__(256) void gemm3_kernel(
    const float* __restrict__ h2, const float* __restrict__ W3,
    const float* __restrict__ b3,
    const int* __restrict__ meta, const int* __restrict__ perm,
    float* __restrict__ out)
{
    constexpr int TM = 256, TK = 32;
    __shared__ float As[TM][36];     // 36 stride: 16B-aligned float4 rows
    __shared__ float Ws[TK][Cn];
    __shared__ int s_off[En + 1];

    const int tid = threadIdx.x;
    if (tid <= En) s_off[tid] = meta[tid];
    __syncthreads();

    int expert = -1, row0 = 0, rows = 0, acc_t = 0;
    const int bx = blockIdx.x;
    for (int e = 0; e < En; e++) {
        int c = s_off[e + 1] - s_off[e];
        int t = (c + TM - 1) / TM;
        if (expert < 0 && bx < acc_t + t) {
            expert = e;
            row0 = s_off[e] + (bx - acc_t) * TM;
            rows = min(TM, s_off[e + 1] - row0);
        }
        acc_t += t;
    }
    if (expert < 0) return;

    const float* Wexp = W3 + (size_t)expert * H2n * Cn;
    const int r0 = (tid >> 2) * 4;     // 4 rows
    const int c0 = (tid & 3) * 10;     // 10 cols

    float acc[4][10];
    #pragma unroll
    for (int i = 0; i < 4; i++)
        #pragma unroll
        for (int j = 0; j < 10; j++) acc[i][j] = 0.f;

    for (int k0 = 0; k0 < H2n; k0 += TK) {
        // A tile: 256 x 32 = 2048 float4 / 256 threads = 8 each
        #pragma unroll
        for (int s = 0; s < 8; s++) {
            int idx = tid + s * 256;
            int m = idx >> 3;
            int k4 = idx & 7;
            float4 v = make_float4(0.f, 0.f, 0.f, 0.f);
            if (m < rows) v = *(const float4*)&h2[(size_t)(row0 + m) * H2n + k0 + k4 * 4];
            *(float4*)&As[m][k4 * 4] = v;
        }
        // W tile: 32 x 40 = 1280 / 256 = 5 each
        #pragma unroll
        for (int s = 0; s < 5; s++) {
            int idx = tid + s * 256;
            int bk = idx / Cn;
            int c = idx - bk * Cn;
            Ws[bk][c] = Wexp[(size_t)(k0 + bk) * Cn + c];
        }
        __syncthreads();

        #pragma unroll 4
        for (int kk = 0; kk < TK; kk++) {
            float w[10];
            #pragma unroll
            for (int j = 0; j < 10; j++) w[j] = Ws[kk][c0 + j];
            #pragma unroll
            for (int i = 0; i < 4; i++) {
                float a = As[r0 + i][kk];
                #pragma unroll
                for (int j = 0; j < 10; j++) acc[i][j] = fmaf(a, w[j], acc[i][j]);
            }
        }
        __syncthreads();
    }

    #pragma unroll
    for (int i = 0; i < 4; i++) {
        int r = r0 + i;
        if (r < rows) {
            int smp = perm[row0 + r];
            #pragma unroll
            for (int j = 0; j < 10; j++) {
                float v = acc[i][j] + b3[expert * Cn + c0 + j];
                out[(size_t)smp * Cn + c0 + j] = v;
            }
        }
    }
}

// ---------------------------------------------------------------------------
extern "C" void kernel_launch(void* const* d_in, const int* in_sizes, int n_in,
                              void* d_out, int out_size, void* d_ws, size_t ws_size,
                              hipStream_t stream)
{
    const float* xs = (const float*)d_in[0];   // x_s
    const float* xp = (const float*)d_in[1];   // x_p  (concat order: [x_p, x_s])
    const float* W1 = (const float*)d_in[2];
    const float* b1 = (const float*)d_in[3];
    const float* W2 = (const float*)d_in[4];
    const float* b2 = (const float*)d_in[5];
    const float* W3 = (const float*)d_in[6];
    const float* b3 = (const float*)d_in[7];
    const int* label = (const int*)d_in[8];
    float* out = (float*)d_out;

    int* meta = (int*)d_ws;                                   // offsets[9]
    int* perm = meta + 16;                                    // [4096]
    float* h1 = (float*)((char*)d_ws + 65536);                // [4096*1024] f32 sorted
    float* h2 = h1 + (size_t)Bn * H1n;                        // [4096*512]  f32 sorted

    route_kernel<<<1, 1024, 0, stream>>>(label, meta, perm);

    // max row-tiles = sum ceil(c_e/64) <= 4096/64 + 8 = 72
    dim3 g1(72, H1n / 128);
    gemm_elu<K1n, H1n, true><<<g1, 256, 0, stream>>>(
        nullptr, xp, xs, W1, b1, meta, perm, h1);

    dim3 g2(72, H2n / 128);
    gemm_elu<H1n, H2n, false><<<g2, 256, 0, stream>>>(
        h1, nullptr, nullptr, W2, b2, meta, perm, h2);

    // max tiles = 4096/256 + 8 = 24
    gemm3_kernel<<<dim3(24, 1), 256, 0, stream>>>(h2, W3, b3, meta, perm, out);
}

// Round 4
// 273.333 us; speedup vs baseline: 2.0544x; 2.0544x over previous
//
#include <hip/hip_runtime.h>
#include <hip/hip_bf16.h>
#include <math.h>

#define En   8
#define Bn   4096
#define Ln   512
#define K1n  1024   // 2L
#define H1n  1024
#define H2n  512
#define Cn   40

typedef unsigned short u16;
typedef __attribute__((ext_vector_type(8))) short bf16x8;   // 8 bf16 = 4 VGPRs
typedef __attribute__((ext_vector_type(4))) float f32x4;

// f32 -> bf16 (RNE), finite inputs
__device__ __forceinline__ u16 f2b(float f) {
    union { float f; unsigned int u; } v; v.f = f;
    unsigned int r = v.u + 0x7FFF + ((v.u >> 16) & 1);
    return (u16)(r >> 16);
}
__device__ __forceinline__ float b2f(u16 u) {
    union { unsigned int u; float f; } v; v.u = ((unsigned int)u) << 16; return v.f;
}

// ---------------------------------------------------------------------------
// Routing: histogram + scan + scatter. meta[0..8] = expert offsets.
// ---------------------------------------------------------------------------
__global__ __launch_bounds__(1024) void route_kernel(
    const int* __restrict__ label, int* __restrict__ meta, int* __restrict__ perm)
{
    __shared__ int cnt[En];
    __shared__ int off[En + 1];
    const int tid = threadIdx.x;
    if (tid < En) cnt[tid] = 0;
    __syncthreads();
    for (int b = tid; b < Bn; b += 1024) atomicAdd(&cnt[label[b]], 1);
    __syncthreads();
    if (tid == 0) {
        int run = 0;
        for (int e = 0; e < En; e++) { off[e] = run; run += cnt[e]; }
        off[En] = run;
    }
    __syncthreads();
    if (tid < En) cnt[tid] = off[tid];
    __syncthreads();
    for (int b = tid; b < Bn; b += 1024) {
        int e = label[b];
        int pos = atomicAdd(&cnt[e], 1);
        perm[pos] = b;
    }
    if (tid <= En) meta[tid] = off[tid];
}

// ---------------------------------------------------------------------------
// Gather + concat + fp32->bf16: Xb[r][k] = bf16(concat(x_p,x_s)[perm[r]][k])
// ---------------------------------------------------------------------------
__global__ __launch_bounds__(256) void xgather_kernel(
    const float* __restrict__ xp, const float* __restrict__ xs,
    const int* __restrict__ perm, u16* __restrict__ Xb)
{
    const int r = blockIdx.x;
    const int smp = perm[r];
    const int tid = threadIdx.x;
    #pragma unroll
    for (int i = 0; i < 4; i++) {
        int k = tid + i * 256;
        float v = (k < Ln) ? xp[(size_t)smp * Ln + k] : xs[(size_t)smp * Ln + (k - Ln)];
        Xb[(size_t)r * K1n + k] = f2b(v);
    }
}

// ---------------------------------------------------------------------------
// W[e][k][n] f32 -> Wt[e][n][k] bf16 (32x32 LDS-tiled transpose + convert)
// grid: (K/32, N/32, E)
// ---------------------------------------------------------------------------
__global__ __launch_bounds__(256) void wtrans_kernel(
    const float* __restrict__ W, u16* __restrict__ Wt, int K, int N)
{
    __shared__ u16 t[32][33];
    const int tid = threadIdx.x;
    const int k0 = blockIdx.x * 32, n0 = blockIdx.y * 32, e = blockIdx.z;
    const float* Wsrc = W + (size_t)e * K * N;
    u16* Wdst = Wt + (size_t)e * N * K;
    #pragma unroll
    for (int s = 0; s < 4; s++) {
        int kk = (tid >> 5) + s * 8;
        int nn = tid & 31;
        t[kk][nn] = f2b(Wsrc[(size_t)(k0 + kk) * N + n0 + nn]);
    }
    __syncthreads();
    #pragma unroll
    for (int s = 0; s < 4; s++) {
        int nn = (tid >> 5) + s * 8;
        int kk = tid & 31;
        Wdst[(size_t)(n0 + nn) * K + k0 + kk] = t[kk][nn];
    }
}

// ---------------------------------------------------------------------------
// Grouped bf16 MFMA GEMM + bias + ELU -> bf16.
// A: [rows][K] bf16 sorted;  Wt: [E][N][K] bf16;  bias: [E][N] f32.
// 128x128 tile / block, 4 waves each 64x64 (4x4 of 16x16x32 MFMA), BK=32.
// ---------------------------------------------------------------------------
template <int K, int N>
__global__ __launch_bounds__(256) void mfma_gemm(
    const u16* __restrict__ A, const u16* __restrict__ Wt,
    const float* __restrict__ bias, const int* __restrict__ meta,
    u16* __restrict__ out)
{
    constexpr int TM = 128, TN = 128, BK = 32;
    __shared__ __align__(16) u16 As[TM * BK];   // [row][k] 64 B/row
    __shared__ __align__(16) u16 Bs[TN * BK];   // [col][k] 64 B/col (W^T tile)
    __shared__ int s_off[En + 1];

    const int tid = threadIdx.x;
    if (tid <= En) s_off[tid] = meta[tid];
    __syncthreads();

    // blockIdx.x -> (expert, row0)
    int expert = -1, row0 = 0, acc_t = 0;
    const int bx = blockIdx.x;
    for (int e = 0; e < En; e++) {
        int c = s_off[e + 1] - s_off[e];
        int t = (c + TM - 1) / TM;
        if (expert < 0 && bx < acc_t + t) {
            expert = e;
            row0 = s_off[e] + (bx - acc_t) * TM;
        }
        acc_t += t;
    }
    if (expert < 0) return;
    const int rowmax = s_off[expert + 1] - 1;   // inclusive

    const int col0 = blockIdx.y * TN;
    const u16* Wexp = Wt + (size_t)expert * N * K;

    const int lane = tid & 63;
    const int wid = tid >> 6;
    const int wm = (wid & 1) * 64;      // wave row-quadrant
    const int wn = (wid >> 1) * 64;     // wave col-quadrant
    const int l15 = lane & 15;
    const int lq = lane >> 4;           // 0..3

    // staging geometry: idx = tid + s*256; row/col = idx>>2 (0..127), kq = idx&3
    const u16* aptr[2];
    const u16* bptr[2];
    #pragma unroll
    for (int s = 0; s < 2; s++) {
        int idx = tid + s * 256;
        int rl = idx >> 2, kq = idx & 3;
        int rg = row0 + rl; if (rg > rowmax) rg = rowmax;
        aptr[s] = A + (size_t)rg * K + kq * 8;
        bptr[s] = Wexp + (size_t)(col0 + rl) * K + kq * 8;
    }

    f32x4 acc[4][4];
    #pragma unroll
    for (int i = 0; i < 4; i++)
        #pragma unroll
        for (int j = 0; j < 4; j++) acc[i][j] = (f32x4){0.f, 0.f, 0.f, 0.f};

    for (int k0 = 0; k0 < K; k0 += BK) {
        #pragma unroll
        for (int s = 0; s < 2; s++) {
            int idx = tid + s * 256;
            int rl = idx >> 2, kq = idx & 3;
            *(uint4*)&As[rl * BK + kq * 8] = *(const uint4*)(aptr[s] + k0);
            *(uint4*)&Bs[rl * BK + kq * 8] = *(const uint4*)(bptr[s] + k0);
        }
        __syncthreads();

        bf16x8 af[4], bf[4];
        #pragma unroll
        for (int i = 0; i < 4; i++)
            af[i] = *(const bf16x8*)&As[(wm + i * 16 + l15) * BK + lq * 8];
        #pragma unroll
        for (int j = 0; j < 4; j++)
            bf[j] = *(const bf16x8*)&Bs[(wn + j * 16 + l15) * BK + lq * 8];

        #pragma unroll
        for (int i = 0; i < 4; i++)
            #pragma unroll
            for (int j = 0; j < 4; j++)
                acc[i][j] = __builtin_amdgcn_mfma_f32_16x16x32_bf16(
                    af[i], bf[j], acc[i][j], 0, 0, 0);
        __syncthreads();
    }

    // epilogue: bias + ELU + cvt bf16.  C/D: col=lane&15, row=lq*4+reg
    #pragma unroll
    for (int i = 0; i < 4; i++) {
        #pragma unroll
        for (int j = 0; j < 4; j++) {
            int col = col0 + wn + j * 16 + l15;
            float bv = bias[expert * N + col];
            #pragma unroll
            for (int r = 0; r < 4; r++) {
                int grow = row0 + wm + i * 16 + lq * 4 + r;
                if (grow <= rowmax) {
                    float v = acc[i][j][r] + bv;
                    v = (v > 0.f) ? v : (expf(v) - 1.f);
                    out[(size_t)grow * N + col] = f2b(v);
                }
            }
        }
    }
}

// ---------------------------------------------------------------------------
// Layer 3: [rows,512] bf16 x [512,40] f32 + b3, scatter to out[perm[r]] f32.
// ---------------------------------------------------------------------------
__global__ __launch_bounds__(256) void gemm3_kernel(
    const u16* __restrict__ h2, const float* __restrict__ W3,
    const float* __restrict__ b3,
    const int* __restrict__ meta, const int* __restrict__ perm,
    float* __restrict__ out)
{
    constexpr int TM = 256, TK = 32;
    __shared__ float As[TM][36];
    __shared__ float Ws[TK][Cn];
    __shared__ int s_off[En + 1];

    const int tid = threadIdx.x;
    if (tid <= En) s_off[tid] = meta[tid];
    __syncthreads();

    int expert = -1, row0 = 0, rows = 0, acc_t = 0;
    const int bx = blockIdx.x;
    for (int e = 0; e < En; e++) {
        int c = s_off[e + 1] - s_off[e];
        int t = (c + TM - 1) / TM;
        if (expert < 0 && bx < acc_t + t) {
            expert = e;
            row0 = s_off[e] + (bx - acc_t) * TM;
            rows = min(TM, s_off[e + 1] - row0);
        }
        acc_t += t;
    }
    if (expert < 0) return;

    const float* Wexp = W3 + (size_t)expert * H2n * Cn;
    const int r0 = (tid >> 2) * 4;
    const int c0 = (tid & 3) * 10;

    float acc[4][10];
    #pragma unroll
    for (int i = 0; i < 4; i++)
        #pragma unroll
        for (int j = 0; j < 10; j++) acc[i][j] = 0.f;

    for (int k0 = 0; k0 < H2n; k0 += TK) {
        // A tile: 256x32 bf16 = 2048 ushort4 / 256 threads = 8 each
        #pragma unroll
        for (int s = 0; s < 8; s++) {
            int idx = tid + s * 256;
            int m = idx >> 3;
            int k4 = idx & 7;
            float4 v = make_float4(0.f, 0.f, 0.f, 0.f);
            if (m < rows) {
                ushort4 h = *(const ushort4*)&h2[(size_t)(row0 + m) * H2n + k0 + k4 * 4];
                v = make_float4(b2f(h.x), b2f(h.y), b2f(h.z), b2f(h.w));
            }
            *(float4*)&As[m][k4 * 4] = v;
        }
        #pragma unroll
        for (int s = 0; s < 5; s++) {
            int idx = tid + s * 256;
            int bk = idx / Cn;
            int c = idx - bk * Cn;
            Ws[bk][c] = Wexp[(size_t)(k0 + bk) * Cn + c];
        }
        __syncthreads();

        #pragma unroll 4
        for (int kk = 0; kk < TK; kk++) {
            float w[10];
            #pragma unroll
            for (int j = 0; j < 10; j++) w[j] = Ws[kk][c0 + j];
            #pragma unroll
            for (int i = 0; i < 4; i++) {
                float a = As[r0 + i][kk];
                #pragma unroll
                for (int j = 0; j < 10; j++) acc[i][j] = fmaf(a, w[j], acc[i][j]);
            }
        }
        __syncthreads();
    }

    #pragma unroll
    for (int i = 0; i < 4; i++) {
        int r = r0 + i;
        if (r < rows) {
            int smp = perm[row0 + r];
            #pragma unroll
            for (int j = 0; j < 10; j++) {
                float v = acc[i][j] + b3[expert * Cn + c0 + j];
                out[(size_t)smp * Cn + c0 + j] = v;
            }
        }
    }
}

// ---------------------------------------------------------------------------
extern "C" void kernel_launch(void* const* d_in, const int* in_sizes, int n_in,
                              void* d_out, int out_size, void* d_ws, size_t ws_size,
                              hipStream_t stream)
{
    const float* xs = (const float*)d_in[0];
    const float* xp = (const float*)d_in[1];
    const float* W1 = (const float*)d_in[2];
    const float* b1 = (const float*)d_in[3];
    const float* W2 = (const float*)d_in[4];
    const float* b2 = (const float*)d_in[5];
    const float* W3 = (const float*)d_in[6];
    const float* b3 = (const float*)d_in[7];
    const int* label = (const int*)d_in[8];
    float* out = (float*)d_out;

    char* ws = (char*)d_ws;
    int* meta = (int*)ws;                       // 64 B
    int* perm = (int*)(ws + 64);                // 16 KB
    u16* Xb  = (u16*)(ws + (64 << 10));         // 8 MB  [4096][1024]
    u16* W1t = (u16*)(ws + (64 << 10) + (8 << 20));            // 16 MB [8][1024][1024]
    u16* W2t = (u16*)(ws + (64 << 10) + (24 << 20));           // 8 MB  [8][512][1024]
    u16* h1b = (u16*)(ws + (64 << 10) + (32 << 20));           // 8 MB  [4096][1024]
    u16* h2b = (u16*)(ws + (64 << 10) + (40 << 20));           // 4 MB  [4096][512]

    route_kernel<<<1, 1024, 0, stream>>>(label, meta, perm);
    xgather_kernel<<<Bn, 256, 0, stream>>>(xp, xs, perm, Xb);
    wtrans_kernel<<<dim3(K1n / 32, H1n / 32, En), 256, 0, stream>>>(W1, W1t, K1n, H1n);
    wtrans_kernel<<<dim3(H1n / 32, H2n / 32, En), 256, 0, stream>>>(W2, W2t, H1n, H2n);

    // row tiles <= 4096/128 + 8 = 40
    mfma_gemm<K1n, H1n><<<dim3(40, H1n / 128), 256, 0, stream>>>(Xb, W1t, b1, meta, h1b);
    mfma_gemm<H1n, H2n><<<dim3(40, H2n / 128), 256, 0, stream>>>(h1b, W2t, b2, meta, h2b);

    gemm3_kernel<<<dim3(24, 1), 256, 0, stream>>>(h2b, W3, b3, meta, perm, out);
}

// Round 5
// 199.897 us; speedup vs baseline: 2.8091x; 1.3674x over previous
//
#include <hip/hip_runtime.h>
#include <hip/hip_bf16.h>
#include <math.h>

#define En   8
#define Bn   4096
#define Ln   512
#define K1n  1024   // 2L
#define H1n  1024
#define H2n  512
#define Cn   40
#define NP3  48     // layer-3 padded N

typedef unsigned short u16;
typedef __attribute__((ext_vector_type(8))) short bf16x8;   // 8 bf16 = 4 VGPRs
typedef __attribute__((ext_vector_type(4))) float f32x4;

// f32 -> bf16 (RNE), finite inputs
__device__ __forceinline__ u16 f2b(float f) {
    union { float f; unsigned int u; } v; v.f = f;
    unsigned int r = v.u + 0x7FFF + ((v.u >> 16) & 1);
    return (u16)(r >> 16);
}

// async global->LDS 16B copy (global_load_lds_dwordx4). LDS dest must be
// wave-uniform base + lane*16 — all call sites use lane-contiguous layouts.
// AS(3) pointer formed from low 32 bits of the generic LDS address (CK idiom).
__device__ __forceinline__ void g2l16(const void* g, void* l) {
    __builtin_amdgcn_global_load_lds(
        (const __attribute__((address_space(1))) unsigned int*)(unsigned long long)g,
        (__attribute__((address_space(3))) unsigned int*)(unsigned int)(unsigned long long)l,
        16, 0, 0);
}

// ---------------------------------------------------------------------------
// Routing: histogram + scan + scatter. meta[0..8] = expert offsets.
// ---------------------------------------------------------------------------
__global__ __launch_bounds__(1024) void route_kernel(
    const int* __restrict__ label, int* __restrict__ meta, int* __restrict__ perm)
{
    __shared__ int cnt[En];
    __shared__ int off[En + 1];
    const int tid = threadIdx.x;
    if (tid < En) cnt[tid] = 0;
    __syncthreads();
    for (int b = tid; b < Bn; b += 1024) atomicAdd(&cnt[label[b]], 1);
    __syncthreads();
    if (tid == 0) {
        int run = 0;
        for (int e = 0; e < En; e++) { off[e] = run; run += cnt[e]; }
        off[En] = run;
    }
    __syncthreads();
    if (tid < En) cnt[tid] = off[tid];
    __syncthreads();
    for (int b = tid; b < Bn; b += 1024) {
        int e = label[b];
        int pos = atomicAdd(&cnt[e], 1);
        perm[pos] = b;
    }
    if (tid <= En) meta[tid] = off[tid];
}

// ---------------------------------------------------------------------------
// Gather + concat + fp32->bf16: Xb[r][k] = bf16(concat(x_p,x_s)[perm[r]][k])
// ---------------------------------------------------------------------------
__global__ __launch_bounds__(256) void xgather_kernel(
    const float* __restrict__ xp, const float* __restrict__ xs,
    const int* __restrict__ perm, u16* __restrict__ Xb)
{
    const int r = blockIdx.x;
    const int smp = perm[r];
    const int tid = threadIdx.x;
    #pragma unroll
    for (int i = 0; i < 4; i++) {
        int k = tid + i * 256;
        float v = (k < Ln) ? xp[(size_t)smp * Ln + k] : xs[(size_t)smp * Ln + (k - Ln)];
        Xb[(size_t)r * K1n + k] = f2b(v);
    }
}

// ---------------------------------------------------------------------------
// W[e][k][n] f32 -> Wt[e][n][k] bf16 (32x32 LDS-tiled transpose + convert)
// ---------------------------------------------------------------------------
__global__ __launch_bounds__(256) void wtrans_kernel(
    const float* __restrict__ W, u16* __restrict__ Wt, int K, int N)
{
    __shared__ u16 t[32][33];
    const int tid = threadIdx.x;
    const int k0 = blockIdx.x * 32, n0 = blockIdx.y * 32, e = blockIdx.z;
    const float* Wsrc = W + (size_t)e * K * N;
    u16* Wdst = Wt + (size_t)e * N * K;
    #pragma unroll
    for (int s = 0; s < 4; s++) {
        int kk = (tid >> 5) + s * 8;
        int nn = tid & 31;
        t[kk][nn] = f2b(Wsrc[(size_t)(k0 + kk) * N + n0 + nn]);
    }
    __syncthreads();
    #pragma unroll
    for (int s = 0; s < 4; s++) {
        int nn = (tid >> 5) + s * 8;
        int kk = tid & 31;
        Wdst[(size_t)(n0 + nn) * K + k0 + kk] = t[kk][nn];
    }
}

// ---------------------------------------------------------------------------
// W3[e][512][40] f32 -> Wt3[e][48][512] bf16 (cols 40..47 zero)
// grid (E, 512/32)
// ---------------------------------------------------------------------------
__global__ __launch_bounds__(256) void w3trans_kernel(
    const float* __restrict__ W3, u16* __restrict__ Wt3)
{
    __shared__ float t[32][41];
    const int e = blockIdx.x, k0 = blockIdx.y * 32;
    const float* src = W3 + (size_t)e * H2n * Cn;
    u16* dst = Wt3 + (size_t)e * NP3 * H2n;
    const int tid = threadIdx.x;
    #pragma unroll
    for (int s = 0; s < 5; s++) {          // 32*40 = 1280 = 5*256
        int idx = tid + s * 256;
        int kk = idx / Cn, nn = idx - kk * Cn;
        if (kk < 32) t[kk][nn] = src[(size_t)(k0 + kk) * Cn + nn];
    }
    __syncthreads();
    #pragma unroll
    for (int s = 0; s < 6; s++) {          // 48*32 = 1536 = 6*256
        int idx = tid + s * 256;
        int nn = idx >> 5, kk = idx & 31;
        float v = (nn < Cn) ? t[kk][nn] : 0.f;
        dst[(size_t)nn * H2n + k0 + kk] = f2b(v);
    }
}

// ---------------------------------------------------------------------------
// Grouped bf16 MFMA GEMM + bias + ELU -> bf16.
// A: [rows][K] bf16 sorted;  Wt: [E][N][K] bf16;  bias: [E][N] f32.
// 128x128 tile, 4 waves each 64x64 (4x4 of 16x16x32 MFMA), BK=32.
// Staging: global_load_lds 16B, k-chunk XOR-swizzled by row&3 (bank spread).
// ---------------------------------------------------------------------------
template <int K, int N>
__global__ __launch_bounds__(256) void mfma_gemm(
    const u16* __restrict__ A, const u16* __restrict__ Wt,
    const float* __restrict__ bias, const int* __restrict__ meta,
    u16* __restrict__ out)
{
    constexpr int TM = 128, TN = 128, BK = 32;
    __shared__ __align__(16) u16 As[TM * BK];   // slot idx*8: row=idx>>2, chunk=idx&3
    __shared__ __align__(16) u16 Bs[TN * BK];
    __shared__ int s_off[En + 1];

    const int tid = threadIdx.x;
    if (tid <= En) s_off[tid] = meta[tid];
    __syncthreads();

    int expert = -1, row0 = 0, acc_t = 0;
    const int bx = blockIdx.x;
    for (int e = 0; e < En; e++) {
        int c = s_off[e + 1] - s_off[e];
        int t = (c + TM - 1) / TM;
        if (expert < 0 && bx < acc_t + t) {
            expert = e;
            row0 = s_off[e] + (bx - acc_t) * TM;
        }
        acc_t += t;
    }
    if (expert < 0) return;
    const int rowmax = s_off[expert + 1] - 1;

    const int col0 = blockIdx.y * TN;
    const u16* Wexp = Wt + (size_t)expert * N * K;

    const int lane = tid & 63;
    const int wid = tid >> 6;
    const int wm = (wid & 1) * 64;
    const int wn = (wid >> 1) * 64;
    const int l15 = lane & 15;
    const int lq = lane >> 4;

    // staging: idx = tid + s*256; rl = idx>>2, chunk pos c = idx&3 holds
    // global k-chunk (c ^ (rl&3)). LDS slot = idx*16 B (lane-contiguous).
    const u16* aptr[2];
    const u16* bptr[2];
    u16* alds[2]; u16* blds[2];
    #pragma unroll
    for (int s = 0; s < 2; s++) {
        int idx = tid + s * 256;
        int rl = idx >> 2, c = idx & 3;
        int kq = c ^ (rl & 3);
        int rg = row0 + rl; if (rg > rowmax) rg = rowmax;
        aptr[s] = A + (size_t)rg * K + kq * 8;
        bptr[s] = Wexp + (size_t)(col0 + rl) * K + kq * 8;
        alds[s] = &As[idx * 8];
        blds[s] = &Bs[idx * 8];
    }

    // frag-read swizzle term (loop-invariant: row&3 == l15&3)
    const int rsw = (0 ^ (l15 & 3));   // chunk holding kq=lq is (lq ^ (row&3))

    f32x4 acc[4][4];
    #pragma unroll
    for (int i = 0; i < 4; i++)
        #pragma unroll
        for (int j = 0; j < 4; j++) acc[i][j] = (f32x4){0.f, 0.f, 0.f, 0.f};

    for (int k0 = 0; k0 < K; k0 += BK) {
        #pragma unroll
        for (int s = 0; s < 2; s++) {
            g2l16(aptr[s] + k0, alds[s]);
            g2l16(bptr[s] + k0, blds[s]);
        }
        __syncthreads();   // drains vmcnt + barrier

        const int ksw = (lq ^ rsw) * 8;
        bf16x8 af[4], bf[4];
        #pragma unroll
        for (int i = 0; i < 4; i++)
            af[i] = *(const bf16x8*)&As[(wm + i * 16 + l15) * BK + ksw];
        #pragma unroll
        for (int j = 0; j < 4; j++)
            bf[j] = *(const bf16x8*)&Bs[(wn + j * 16 + l15) * BK + ksw];

        #pragma unroll
        for (int i = 0; i < 4; i++)
            #pragma unroll
            for (int j = 0; j < 4; j++)
                acc[i][j] = __builtin_amdgcn_mfma_f32_16x16x32_bf16(
                    af[i], bf[j], acc[i][j], 0, 0, 0);
        __syncthreads();   // protect LDS before next iter's async writes
    }

    // epilogue: bias + ELU + cvt bf16.  C/D: col=lane&15, row=lq*4+reg
    #pragma unroll
    for (int i = 0; i < 4; i++) {
        #pragma unroll
        for (int j = 0; j < 4; j++) {
            int col = col0 + wn + j * 16 + l15;
            float bv = bias[expert * N + col];
            #pragma unroll
            for (int r = 0; r < 4; r++) {
                int grow = row0 + wm + i * 16 + lq * 4 + r;
                if (grow <= rowmax) {
                    float v = acc[i][j][r] + bv;
                    v = (v > 0.f) ? v : (expf(v) - 1.f);
                    out[(size_t)grow * N + col] = f2b(v);
                }
            }
        }
    }
}

// ---------------------------------------------------------------------------
// Layer 3 MFMA: [rows,512] bf16 x Wt3[E][48][512] bf16 + b3 -> scatter f32.
// 64-row tile, 4 waves (wave = 16 rows x 48 cols), BK=32, 16 K-iters.
// ---------------------------------------------------------------------------
__global__ __launch_bounds__(256) void gemm3_mfma(
    const u16* __restrict__ h2, const u16* __restrict__ Wt3,
    const float* __restrict__ b3, const int* __restrict__ meta,
    const int* __restrict__ perm, float* __restrict__ out)
{
    constexpr int TM = 64, BK = 32;
    __shared__ __align__(16) u16 As[TM * BK];    // 4 KB
    __shared__ __align__(16) u16 Bs[NP3 * BK];   // 3 KB
    __shared__ int s_off[En + 1];

    const int tid = threadIdx.x;
    if (tid <= En) s_off[tid] = meta[tid];
    __syncthreads();

    int expert = -1, row0 = 0, acc_t = 0;
    const int bx = blockIdx.x;
    for (int e = 0; e < En; e++) {
        int c = s_off[e + 1] - s_off[e];
        int t = (c + TM - 1) / TM;
        if (expert < 0 && bx < acc_t + t) {
            expert = e;
            row0 = s_off[e] + (bx - acc_t) * TM;
        }
        acc_t += t;
    }
    if (expert < 0) return;
    const int rowmax = s_off[expert + 1] - 1;

    const int lane = tid & 63;
    const int wid = tid >> 6;
    const int l15 = lane & 15;
    const int lq = lane >> 4;

    // staging: A 64 rows x 4 chunks = 256 slots (1/thread); B 48x4 = 192 slots
    const int rl = tid >> 2, c = tid & 3;
    const int kq = c ^ (rl & 3);
    int rg = row0 + rl; if (rg > rowmax) rg = rowmax;
    const u16* ag = h2 + (size_t)rg * H2n + kq * 8;
    const u16* bg = Wt3 + (size_t)expert * NP3 * H2n + (size_t)rl * H2n + kq * 8;
    u16* al = &As[tid * 8];
    u16* bl = &Bs[tid * 8];

    f32x4 acc[3];
    #pragma unroll
    for (int j = 0; j < 3; j++) acc[j] = (f32x4){0.f, 0.f, 0.f, 0.f};

    for (int k0 = 0; k0 < H2n; k0 += BK) {
        g2l16(ag + k0, al);
        if (tid < NP3 * 4) g2l16(bg + k0, bl);
        __syncthreads();

        const int ksw = (lq ^ (l15 & 3)) * 8;
        bf16x8 af = *(const bf16x8*)&As[(wid * 16 + l15) * BK + ksw];
        bf16x8 bf[3];
        #pragma unroll
        for (int j = 0; j < 3; j++)
            bf[j] = *(const bf16x8*)&Bs[(j * 16 + l15) * BK + ksw];
        #pragma unroll
        for (int j = 0; j < 3; j++)
            acc[j] = __builtin_amdgcn_mfma_f32_16x16x32_bf16(af, bf[j], acc[j], 0, 0, 0);
        __syncthreads();
    }

    #pragma unroll
    for (int j = 0; j < 3; j++) {
        int col = j * 16 + l15;
        if (col < Cn) {
            float bv = b3[expert * Cn + col];
            #pragma unroll
            for (int r = 0; r < 4; r++) {
                int grow = row0 + wid * 16 + lq * 4 + r;
                if (grow <= rowmax) {
                    int smp = perm[grow];
                    out[(size_t)smp * Cn + col] = acc[j][r] + bv;
                }
            }
        }
    }
}

// ---------------------------------------------------------------------------
extern "C" void kernel_launch(void* const* d_in, const int* in_sizes, int n_in,
                              void* d_out, int out_size, void* d_ws, size_t ws_size,
                              hipStream_t stream)
{
    const float* xs = (const float*)d_in[0];
    const float* xp = (const float*)d_in[1];
    const float* W1 = (const float*)d_in[2];
    const float* b1 = (const float*)d_in[3];
    const float* W2 = (const float*)d_in[4];
    const float* b2 = (const float*)d_in[5];
    const float* W3 = (const float*)d_in[6];
    const float* b3 = (const float*)d_in[7];
    const int* label = (const int*)d_in[8];
    float* out = (float*)d_out;

    char* ws = (char*)d_ws;
    int* meta = (int*)ws;                                    // 64 B
    int* perm = (int*)(ws + 64);                             // 16 KB
    u16* Xb  = (u16*)(ws + (64 << 10));                      // 8 MB [4096][1024]
    u16* h2b = Xb;                                           // alias: Xb dead after L1
    u16* W1t = (u16*)(ws + (64 << 10) + (8  << 20));         // 16 MB [8][1024][1024]
    u16* W2t = (u16*)(ws + (64 << 10) + (24 << 20));         // 8 MB  [8][512][1024]
    u16* h1b = (u16*)(ws + (64 << 10) + (32 << 20));         // 8 MB  [4096][1024]
    u16* W3t = (u16*)(ws + (64 << 10) + (40 << 20));         // 393 KB [8][48][512]

    route_kernel<<<1, 1024, 0, stream>>>(label, meta, perm);
    xgather_kernel<<<Bn, 256, 0, stream>>>(xp, xs, perm, Xb);
    wtrans_kernel<<<dim3(K1n / 32, H1n / 32, En), 256, 0, stream>>>(W1, W1t, K1n, H1n);
    wtrans_kernel<<<dim3(H1n / 32, H2n / 32, En), 256, 0, stream>>>(W2, W2t, H1n, H2n);
    w3trans_kernel<<<dim3(En, H2n / 32), 256, 0, stream>>>(W3, W3t);

    // row tiles <= 4096/128 + 8 = 40
    mfma_gemm<K1n, H1n><<<dim3(40, H1n / 128), 256, 0, stream>>>(Xb, W1t, b1, meta, h1b);
    mfma_gemm<H1n, H2n><<<dim3(40, H2n / 128), 256, 0, stream>>>(h1b, W2t, b2, meta, h2b);

    // row tiles <= 4096/64 + 8 = 72
    gemm3_mfma<<<72, 256, 0, stream>>>(h2b, W3t, b3, meta, perm, out);
}

// Round 6
// 192.801 us; speedup vs baseline: 2.9125x; 1.0368x over previous
//
#include <hip/hip_runtime.h>
#include <hip/hip_bf16.h>
#include <math.h>

#define En   8
#define Bn   4096
#define Ln   512
#define K1n  1024   // 2L
#define H1n  1024
#define H2n  512
#define Cn   40
#define NP3  48     // layer-3 padded N

typedef unsigned short u16;
typedef __attribute__((ext_vector_type(8))) short bf16x8;   // 8 bf16 = 4 VGPRs
typedef __attribute__((ext_vector_type(4))) float f32x4;

// f32 -> bf16 (RNE), finite inputs
__device__ __forceinline__ u16 f2b(float f) {
    union { float f; unsigned int u; } v; v.f = f;
    unsigned int r = v.u + 0x7FFF + ((v.u >> 16) & 1);
    return (u16)(r >> 16);
}

// async global->LDS 16B copy (global_load_lds_dwordx4). LDS dest must be
// wave-uniform base + lane*16 — all call sites use lane-contiguous layouts.
__device__ __forceinline__ void g2l16(const void* g, void* l) {
    __builtin_amdgcn_global_load_lds(
        (const __attribute__((address_space(1))) unsigned int*)(unsigned long long)g,
        (__attribute__((address_space(3))) unsigned int*)(unsigned int)(unsigned long long)l,
        16, 0, 0);
}

// ---------------------------------------------------------------------------
// Mega-prep: block-partitioned fusion of 5 independent jobs.
//   block 0                  : routing (histogram+scan+scatter -> meta, perm)
//   blocks 1..256            : x concat + f32->bf16, ORIGINAL order -> Xb
//   blocks 257..2304         : W1 [e][k][n] f32 -> W1t [e][n][k] bf16 (64x64 tiles)
//   blocks 2305..3328        : W2 likewise
//   blocks 3329..3456        : W3 [e][512][40] -> W3t [e][48][512] bf16, pad 0
// ---------------------------------------------------------------------------
#define PB_X0   1
#define PB_X    256
#define PB_W1   2048   // (1024/64)*(1024/64)*8
#define PB_W2   1024   // (1024/64)*(512/64)*8
#define PB_W3   128    // 8 * (512/32)
#define PB_TOT  (PB_X0 + PB_X + PB_W1 + PB_W2 + PB_W3)

__device__ __forceinline__ void wtrans64(
    const float* __restrict__ Wsrc, u16* __restrict__ Wdst,
    int K, int N, int k0, int n0, int tid, float* sm /* [64][65] */)
{
    #pragma unroll
    for (int s = 0; s < 4; s++) {
        int idx = tid + s * 256;
        int kk = idx >> 4, c4 = (idx & 15) * 4;
        float4 v = *(const float4*)&Wsrc[(size_t)(k0 + kk) * N + n0 + c4];
        float* row = sm + kk * 65 + c4;
        row[0] = v.x; row[1] = v.y; row[2] = v.z; row[3] = v.w;
    }
    __syncthreads();
    #pragma unroll
    for (int s = 0; s < 4; s++) {
        int idx = tid + s * 256;
        int nn = idx >> 4, kc = (idx & 15) * 4;
        ushort4 o = make_ushort4(f2b(sm[(kc + 0) * 65 + nn]), f2b(sm[(kc + 1) * 65 + nn]),
                                 f2b(sm[(kc + 2) * 65 + nn]), f2b(sm[(kc + 3) * 65 + nn]));
        *(ushort4*)&Wdst[(size_t)(n0 + nn) * K + k0 + kc] = o;
    }
}

__global__ __launch_bounds__(256) void prep_kernel(
    const float* __restrict__ xs, const float* __restrict__ xp,
    const float* __restrict__ W1, const float* __restrict__ W2,
    const float* __restrict__ W3, const int* __restrict__ label,
    int* __restrict__ meta, int* __restrict__ perm,
    u16* __restrict__ Xb, u16* __restrict__ W1t,
    u16* __restrict__ W2t, u16* __restrict__ W3t)
{
    __shared__ __align__(16) float sm[64 * 65];   // 16.6 KB, reused per role
    const int bid = blockIdx.x;
    const int tid = threadIdx.x;

    if (bid == 0) {
        // ---- routing ----
        int* cnt = (int*)sm;
        int* off = cnt + En;
        if (tid < En) cnt[tid] = 0;
        __syncthreads();
        for (int b = tid; b < Bn; b += 256) atomicAdd(&cnt[label[b]], 1);
        __syncthreads();
        if (tid == 0) {
            int run = 0;
            for (int e = 0; e < En; e++) { off[e] = run; run += cnt[e]; }
            off[En] = run;
        }
        __syncthreads();
        if (tid < En) cnt[tid] = off[tid];
        __syncthreads();
        for (int b = tid; b < Bn; b += 256) {
            int e = label[b];
            perm[atomicAdd(&cnt[e], 1)] = b;
        }
        if (tid <= En) meta[tid] = off[tid];
    } else if (bid < PB_X0 + PB_X) {
        // ---- x concat + convert (original order), 16 rows/block ----
        int r0 = (bid - PB_X0) * 16;
        #pragma unroll 4
        for (int s = 0; s < 16; s++) {
            int r = r0 + s;
            int k = tid * 4;   // 4-chunks never straddle the 512 boundary
            const float* src = (k < Ln) ? (xp + (size_t)r * Ln + k)
                                        : (xs + (size_t)r * Ln + (k - Ln));
            float4 v = *(const float4*)src;
            *(ushort4*)&Xb[(size_t)r * K1n + k] =
                make_ushort4(f2b(v.x), f2b(v.y), f2b(v.z), f2b(v.w));
        }
    } else if (bid < PB_X0 + PB_X + PB_W1) {
        int b = bid - (PB_X0 + PB_X);
        int e = b >> 8, rem = b & 255;           // 16x16 tiles
        int k0 = (rem >> 4) * 64, n0 = (rem & 15) * 64;
        wtrans64(W1 + (size_t)e * K1n * H1n, W1t + (size_t)e * H1n * K1n,
                 K1n, H1n, k0, n0, tid, sm);
    } else if (bid < PB_X0 + PB_X + PB_W1 + PB_W2) {
        int b = bid - (PB_X0 + PB_X + PB_W1);
        int e = b >> 7, rem = b & 127;           // 16(k) x 8(n) tiles
        int k0 = (rem >> 3) * 64, n0 = (rem & 7) * 64;
        wtrans64(W2 + (size_t)e * H1n * H2n, W2t + (size_t)e * H2n * H1n,
                 H1n, H2n, k0, n0, tid, sm);
    } else {
        // ---- W3: [512][40] f32 -> [48][512] bf16 (pad cols 40..47 with 0) ----
        int b = bid - (PB_X0 + PB_X + PB_W1 + PB_W2);
        int e = b >> 4, k0 = (b & 15) * 32;
        const float* src = W3 + (size_t)e * H2n * Cn;
        u16* dst = W3t + (size_t)e * NP3 * H2n;
        float* t = sm;                            // [32][41]
        #pragma unroll
        for (int s = 0; s < 5; s++) {             // 32*40 = 1280
            int idx = tid + s * 256;
            int kk = idx / Cn, nn = idx - kk * Cn;
            if (kk < 32) t[kk * 41 + nn] = src[(size_t)(k0 + kk) * Cn + nn];
        }
        __syncthreads();
        #pragma unroll
        for (int s = 0; s < 6; s++) {             // 48*32 = 1536
            int idx = tid + s * 256;
            int nn = idx >> 5, kk = idx & 31;
            float v = (nn < Cn) ? t[kk * 41 + nn] : 0.f;
            dst[(size_t)nn * H2n + k0 + kk] = f2b(v);
        }
    }
}

// ---------------------------------------------------------------------------
// Grouped bf16 MFMA GEMM + bias + ELU -> bf16.
// A: [.][K] bf16 (GATHER: original order, indexed via perm; else sorted);
// Wt: [E][N][K] bf16; bias: [E][N] f32.
// 128x128 tile, 4 waves each 64x64 (4x4 of 16x16x32 MFMA), BK=32.
// Staging: global_load_lds 16B, k-chunk XOR-swizzled by row&3.
// ---------------------------------------------------------------------------
template <int K, int N, bool GATHER>
__global__ __launch_bounds__(256) void mfma_gemm(
    const u16* __restrict__ A, const u16* __restrict__ Wt,
    const float* __restrict__ bias, const int* __restrict__ meta,
    const int* __restrict__ perm, u16* __restrict__ out)
{
    constexpr int TM = 128, TN = 128, BK = 32;
    __shared__ __align__(16) u16 As[TM * BK];
    __shared__ __align__(16) u16 Bs[TN * BK];
    __shared__ int s_off[En + 1];

    const int tid = threadIdx.x;
    if (tid <= En) s_off[tid] = meta[tid];
    __syncthreads();

    int expert = -1, row0 = 0, acc_t = 0;
    const int bx = blockIdx.x;
    for (int e = 0; e < En; e++) {
        int c = s_off[e + 1] - s_off[e];
        int t = (c + TM - 1) / TM;
        if (expert < 0 && bx < acc_t + t) {
            expert = e;
            row0 = s_off[e] + (bx - acc_t) * TM;
        }
        acc_t += t;
    }
    if (expert < 0) return;
    const int rowmax = s_off[expert + 1] - 1;

    const int col0 = blockIdx.y * TN;
    const u16* Wexp = Wt + (size_t)expert * N * K;

    const int lane = tid & 63;
    const int wid = tid >> 6;
    const int wm = (wid & 1) * 64;
    const int wn = (wid >> 1) * 64;
    const int l15 = lane & 15;
    const int lq = lane >> 4;

    // staging: idx = tid + s*256; rl = idx>>2; chunk slot c=idx&3 holds global
    // k-chunk (c ^ (rl&3)); LDS slot = idx*16 B (lane-contiguous for async).
    const u16* aptr[2];
    const u16* bptr[2];
    u16* alds[2]; u16* blds[2];
    #pragma unroll
    for (int s = 0; s < 2; s++) {
        int idx = tid + s * 256;
        int rl = idx >> 2, c = idx & 3;
        int kq = c ^ (rl & 3);
        int rg = row0 + rl; if (rg > rowmax) rg = rowmax;
        if (GATHER) rg = perm[rg];
        aptr[s] = A + (size_t)rg * K + kq * 8;
        bptr[s] = Wexp + (size_t)(col0 + rl) * K + kq * 8;
        alds[s] = &As[idx * 8];
        blds[s] = &Bs[idx * 8];
    }

    const int rsw = l15 & 3;

    f32x4 acc[4][4];
    #pragma unroll
    for (int i = 0; i < 4; i++)
        #pragma unroll
        for (int j = 0; j < 4; j++) acc[i][j] = (f32x4){0.f, 0.f, 0.f, 0.f};

    for (int k0 = 0; k0 < K; k0 += BK) {
        #pragma unroll
        for (int s = 0; s < 2; s++) {
            g2l16(aptr[s] + k0, alds[s]);
            g2l16(bptr[s] + k0, blds[s]);
        }
        __syncthreads();

        const int ksw = (lq ^ rsw) * 8;
        bf16x8 af[4], bf[4];
        #pragma unroll
        for (int i = 0; i < 4; i++)
            af[i] = *(const bf16x8*)&As[(wm + i * 16 + l15) * BK + ksw];
        #pragma unroll
        for (int j = 0; j < 4; j++)
            bf[j] = *(const bf16x8*)&Bs[(wn + j * 16 + l15) * BK + ksw];

        #pragma unroll
        for (int i = 0; i < 4; i++)
            #pragma unroll
            for (int j = 0; j < 4; j++)
                acc[i][j] = __builtin_amdgcn_mfma_f32_16x16x32_bf16(
                    af[i], bf[j], acc[i][j], 0, 0, 0);
        __syncthreads();
    }

    // epilogue: bias + ELU + cvt bf16.  C/D: col=lane&15, row=lq*4+reg
    #pragma unroll
    for (int i = 0; i < 4; i++) {
        #pragma unroll
        for (int j = 0; j < 4; j++) {
            int col = col0 + wn + j * 16 + l15;
            float bv = bias[expert * N + col];
            #pragma unroll
            for (int r = 0; r < 4; r++) {
                int grow = row0 + wm + i * 16 + lq * 4 + r;
                if (grow <= rowmax) {
                    float v = acc[i][j][r] + bv;
                    v = (v > 0.f) ? v : (expf(v) - 1.f);
                    out[(size_t)grow * N + col] = f2b(v);
                }
            }
        }
    }
}

// ---------------------------------------------------------------------------
// Layer 3 MFMA: [rows,512] bf16 x Wt3[E][48][512] bf16 + b3 -> scatter f32.
// 64-row tile, 4 waves (wave = 16 rows x 48 cols), BK=32, 16 K-iters.
// ---------------------------------------------------------------------------
__global__ __launch_bounds__(256) void gemm3_mfma(
    const u16* __restrict__ h2, const u16* __restrict__ Wt3,
    const float* __restrict__ b3, const int* __restrict__ meta,
    const int* __restrict__ perm, float* __restrict__ out)
{
    constexpr int TM = 64, BK = 32;
    __shared__ __align__(16) u16 As[TM * BK];
    __shared__ __align__(16) u16 Bs[NP3 * BK];
    __shared__ int s_off[En + 1];

    const int tid = threadIdx.x;
    if (tid <= En) s_off[tid] = meta[tid];
    __syncthreads();

    int expert = -1, row0 = 0, acc_t = 0;
    const int bx = blockIdx.x;
    for (int e = 0; e < En; e++) {
        int c = s_off[e + 1] - s_off[e];
        int t = (c + TM - 1) / TM;
        if (expert < 0 && bx < acc_t + t) {
            expert = e;
            row0 = s_off[e] + (bx - acc_t) * TM;
        }
        acc_t += t;
    }
    if (expert < 0) return;
    const int rowmax = s_off[expert + 1] - 1;

    const int lane = tid & 63;
    const int wid = tid >> 6;
    const int l15 = lane & 15;
    const int lq = lane >> 4;

    const int rl = tid >> 2, c = tid & 3;
    const int kq = c ^ (rl & 3);
    int rg = row0 + rl; if (rg > rowmax) rg = rowmax;
    const u16* ag = h2 + (size_t)rg * H2n + kq * 8;
    const u16* bg = Wt3 + (size_t)expert * NP3 * H2n + (size_t)rl * H2n + kq * 8;
    u16* al = &As[tid * 8];
    u16* bl = &Bs[tid * 8];

    f32x4 acc[3];
    #pragma unroll
    for (int j = 0; j < 3; j++) acc[j] = (f32x4){0.f, 0.f, 0.f, 0.f};

    for (int k0 = 0; k0 < H2n; k0 += BK) {
        g2l16(ag + k0, al);
        if (tid < NP3 * 4) g2l16(bg + k0, bl);
        __syncthreads();

        const int ksw = (lq ^ (l15 & 3)) * 8;
        bf16x8 af = *(const bf16x8*)&As[(wid * 16 + l15) * BK + ksw];
        bf16x8 bf[3];
        #pragma unroll
        for (int j = 0; j < 3; j++)
            bf[j] = *(const bf16x8*)&Bs[(j * 16 + l15) * BK + ksw];
        #pragma unroll
        for (int j = 0; j < 3; j++)
            acc[j] = __builtin_amdgcn_mfma_f32_16x16x32_bf16(af, bf[j], acc[j], 0, 0, 0);
        __syncthreads();
    }

    #pragma unroll
    for (int j = 0; j < 3; j++) {
        int col = j * 16 + l15;
        if (col < Cn) {
            float bv = b3[expert * Cn + col];
            #pragma unroll
            for (int r = 0; r < 4; r++) {
                int grow = row0 + wid * 16 + lq * 4 + r;
                if (grow <= rowmax) {
                    int smp = perm[grow];
                    out[(size_t)smp * Cn + col] = acc[j][r] + bv;
                }
            }
        }
    }
}

// ---------------------------------------------------------------------------
extern "C" void kernel_launch(void* const* d_in, const int* in_sizes, int n_in,
                              void* d_out, int out_size, void* d_ws, size_t ws_size,
                              hipStream_t stream)
{
    const float* xs = (const float*)d_in[0];
    const float* xp = (const float*)d_in[1];
    const float* W1 = (const float*)d_in[2];
    const float* b1 = (const float*)d_in[3];
    const float* W2 = (const float*)d_in[4];
    const float* b2 = (const float*)d_in[5];
    const float* W3 = (const float*)d_in[6];
    const float* b3 = (const float*)d_in[7];
    const int* label = (const int*)d_in[8];
    float* out = (float*)d_out;

    char* ws = (char*)d_ws;
    int* meta = (int*)ws;                                    // 64 B
    int* perm = (int*)(ws + 64);                             // 16 KB
    u16* Xb  = (u16*)(ws + (64 << 10));                      // 8 MB [4096][1024] (original order)
    u16* h2b = Xb;                                           // alias: Xb dead after L1
    u16* W1t = (u16*)(ws + (64 << 10) + (8  << 20));         // 16 MB [8][1024][1024]
    u16* W2t = (u16*)(ws + (64 << 10) + (24 << 20));         // 8 MB  [8][512][1024]
    u16* h1b = (u16*)(ws + (64 << 10) + (32 << 20));         // 8 MB  [4096][1024] (sorted)
    u16* W3t = (u16*)(ws + (64 << 10) + (40 << 20));         // 393 KB [8][48][512]

    prep_kernel<<<PB_TOT, 256, 0, stream>>>(
        xs, xp, W1, W2, W3, label, meta, perm, Xb, W1t, W2t, W3t);

    // row tiles <= 4096/128 + 8 = 40
    mfma_gemm<K1n, H1n, true><<<dim3(40, H1n / 128), 256, 0, stream>>>(
        Xb, W1t, b1, meta, perm, h1b);
    mfma_gemm<H1n, H2n, false><<<dim3(40, H2n / 128), 256, 0, stream>>>(
        h1b, W2t, b2, meta, perm, h2b);

    // row tiles <= 4096/64 + 8 = 72
    gemm3_mfma<<<72, 256, 0, stream>>>(h2b, W3t, b3, meta, perm, out);
}

// Round 7
// 180.932 us; speedup vs baseline: 3.1036x; 1.0656x over previous
//
#include <hip/hip_runtime.h>
#include <hip/hip_bf16.h>
#include <math.h>

#define En   8
#define Bn   4096
#define Ln   512
#define K1n  1024   // 2L
#define H1n  1024
#define H2n  512
#define Cn   40
#define NP3  48     // layer-3 padded N

typedef unsigned short u16;
typedef __attribute__((ext_vector_type(8))) short bf16x8;   // 8 bf16 = 4 VGPRs
typedef __attribute__((ext_vector_type(4))) float f32x4;

// f32 -> bf16 (RNE), finite inputs
__device__ __forceinline__ u16 f2b(float f) {
    union { float f; unsigned int u; } v; v.f = f;
    unsigned int r = v.u + 0x7FFF + ((v.u >> 16) & 1);
    return (u16)(r >> 16);
}

// async global->LDS 16B copy (global_load_lds_dwordx4). LDS dest must be
// wave-uniform base + lane*16 — all call sites use lane-contiguous slots.
__device__ __forceinline__ void g2l16(const void* g, void* l) {
    __builtin_amdgcn_global_load_lds(
        (const __attribute__((address_space(1))) unsigned int*)(unsigned long long)g,
        (__attribute__((address_space(3))) unsigned int*)(unsigned int)(unsigned long long)l,
        16, 0, 0);
}

// ---------------------------------------------------------------------------
// Mega-prep, block-partitioned independent jobs:
//   0                : routing -> meta, perm
//   1..256           : x concat + f32->bf16 (original order) -> Xb
//   ..+2048          : W1 [e][k][n] f32 -> W1t [e][n][k] bf16
//   ..+1024          : W2 likewise
//   ..+128           : W3 [e][512][40] -> W3t [e][48][512] bf16 (pad 0)
//   ..+64            : out[b][c] = b3[label[b]][c]   (bias pre-init for L3 atomics)
// ---------------------------------------------------------------------------
#define PB_X0   1
#define PB_X    256
#define PB_W1   2048
#define PB_W2   1024
#define PB_W3   128
#define PB_OUT  64
#define PB_TOT  (PB_X0 + PB_X + PB_W1 + PB_W2 + PB_W3 + PB_OUT)

__device__ __forceinline__ void wtrans64(
    const float* __restrict__ Wsrc, u16* __restrict__ Wdst,
    int K, int N, int k0, int n0, int tid, float* sm /* [64][65] */)
{
    #pragma unroll
    for (int s = 0; s < 4; s++) {
        int idx = tid + s * 256;
        int kk = idx >> 4, c4 = (idx & 15) * 4;
        float4 v = *(const float4*)&Wsrc[(size_t)(k0 + kk) * N + n0 + c4];
        float* row = sm + kk * 65 + c4;
        row[0] = v.x; row[1] = v.y; row[2] = v.z; row[3] = v.w;
    }
    __syncthreads();
    #pragma unroll
    for (int s = 0; s < 4; s++) {
        int idx = tid + s * 256;
        int nn = idx >> 4, kc = (idx & 15) * 4;
        ushort4 o = make_ushort4(f2b(sm[(kc + 0) * 65 + nn]), f2b(sm[(kc + 1) * 65 + nn]),
                                 f2b(sm[(kc + 2) * 65 + nn]), f2b(sm[(kc + 3) * 65 + nn]));
        *(ushort4*)&Wdst[(size_t)(n0 + nn) * K + k0 + kc] = o;
    }
}

__global__ __launch_bounds__(256) void prep_kernel(
    const float* __restrict__ xs, const float* __restrict__ xp,
    const float* __restrict__ W1, const float* __restrict__ W2,
    const float* __restrict__ W3, const float* __restrict__ b3,
    const int* __restrict__ label,
    int* __restrict__ meta, int* __restrict__ perm,
    u16* __restrict__ Xb, u16* __restrict__ W1t,
    u16* __restrict__ W2t, u16* __restrict__ W3t,
    float* __restrict__ out)
{
    __shared__ __align__(16) float sm[64 * 65];
    const int bid = blockIdx.x;
    const int tid = threadIdx.x;

    if (bid == 0) {
        // ---- routing ----
        int* cnt = (int*)sm;
        int* off = cnt + En;
        if (tid < En) cnt[tid] = 0;
        __syncthreads();
        for (int b = tid; b < Bn; b += 256) atomicAdd(&cnt[label[b]], 1);
        __syncthreads();
        if (tid == 0) {
            int run = 0;
            for (int e = 0; e < En; e++) { off[e] = run; run += cnt[e]; }
            off[En] = run;
        }
        __syncthreads();
        if (tid < En) cnt[tid] = off[tid];
        __syncthreads();
        for (int b = tid; b < Bn; b += 256) {
            int e = label[b];
            perm[atomicAdd(&cnt[e], 1)] = b;
        }
        if (tid <= En) meta[tid] = off[tid];
    } else if (bid < PB_X0 + PB_X) {
        // ---- x concat + convert (original order), 16 rows/block ----
        int r0 = (bid - PB_X0) * 16;
        #pragma unroll 4
        for (int s = 0; s < 16; s++) {
            int r = r0 + s;
            int k = tid * 4;
            const float* src = (k < Ln) ? (xp + (size_t)r * Ln + k)
                                        : (xs + (size_t)r * Ln + (k - Ln));
            float4 v = *(const float4*)src;
            *(ushort4*)&Xb[(size_t)r * K1n + k] =
                make_ushort4(f2b(v.x), f2b(v.y), f2b(v.z), f2b(v.w));
        }
    } else if (bid < PB_X0 + PB_X + PB_W1) {
        int b = bid - (PB_X0 + PB_X);
        int e = b >> 8, rem = b & 255;
        int k0 = (rem >> 4) * 64, n0 = (rem & 15) * 64;
        wtrans64(W1 + (size_t)e * K1n * H1n, W1t + (size_t)e * H1n * K1n,
                 K1n, H1n, k0, n0, tid, sm);
    } else if (bid < PB_X0 + PB_X + PB_W1 + PB_W2) {
        int b = bid - (PB_X0 + PB_X + PB_W1);
        int e = b >> 7, rem = b & 127;
        int k0 = (rem >> 3) * 64, n0 = (rem & 7) * 64;
        wtrans64(W2 + (size_t)e * H1n * H2n, W2t + (size_t)e * H2n * H1n,
                 H1n, H2n, k0, n0, tid, sm);
    } else if (bid < PB_X0 + PB_X + PB_W1 + PB_W2 + PB_W3) {
        // ---- W3: [512][40] f32 -> [48][512] bf16, pad cols 40..47 ----
        int b = bid - (PB_X0 + PB_X + PB_W1 + PB_W2);
        int e = b >> 4, k0 = (b & 15) * 32;
        const float* src = W3 + (size_t)e * H2n * Cn;
        u16* dst = W3t + (size_t)e * NP3 * H2n;
        float* t = sm;                            // [32][41]
        #pragma unroll
        for (int s = 0; s < 5; s++) {
            int idx = tid + s * 256;
            int kk = idx / Cn, nn = idx - kk * Cn;
            if (kk < 32) t[kk * 41 + nn] = src[(size_t)(k0 + kk) * Cn + nn];
        }
        __syncthreads();
        #pragma unroll
        for (int s = 0; s < 6; s++) {
            int idx = tid + s * 256;
            int nn = idx >> 5, kk = idx & 31;
            float v = (nn < Cn) ? t[kk * 41 + nn] : 0.f;
            dst[(size_t)nn * H2n + k0 + kk] = f2b(v);
        }
    } else {
        // ---- out bias pre-init: out[r][c] = b3[label[r]][c], 64 rows/block ----
        int b = bid - (PB_X0 + PB_X + PB_W1 + PB_W2 + PB_W3);
        int r0 = b * 64;
        #pragma unroll
        for (int s = 0; s < 10; s++) {            // 64*40 = 2560 = 10*256
            int idx = tid + s * 256;
            int r = r0 + idx / Cn;
            int c = idx - (idx / Cn) * Cn;
            out[(size_t)r * Cn + c] = b3[label[r] * Cn + c];
        }
    }
}

// ---------------------------------------------------------------------------
// Grouped bf16 MFMA GEMM, 128x128 tile, BK=64, double-buffered async K-loop.
// A: [.][K] bf16 (GATHER: original order via perm; else sorted);
// Wt: [E][N][K] bf16; bias: [E][N] f32.
// FUSE3: instead of writing h to global, run layer-3 k-split in the epilogue:
//   h-tile -> LDS -> MFMA vs Wt3[E][48][512] -> atomicAdd f32 into outf
//   (outf pre-initialized with b3 by prep).
// ---------------------------------------------------------------------------
template <int K, int N, bool GATHER, bool FUSE3>
__global__ __launch_bounds__(256) void mfma_gemm(
    const u16* __restrict__ A, const u16* __restrict__ Wt,
    const float* __restrict__ bias, const int* __restrict__ meta,
    const int* __restrict__ perm, u16* __restrict__ outb,
    const u16* __restrict__ Wt3, float* __restrict__ outf)
{
    constexpr int TM = 128, TN = 128, BK = 64;
    constexpr int T = K / BK;
    __shared__ __align__(16) u16 SM[32768];   // 2 stages x (A 8K + B 8K) u16 = 64 KB

    const int tid = threadIdx.x;
    const int bx = blockIdx.x;

    // block -> (expert, row0, rowmax), uniform scalar loads of meta
    int expert = -1, row0 = 0, rowmax = 0, acc_t = 0;
    int prev = meta[0];
    #pragma unroll
    for (int e = 0; e < En; e++) {
        int nxt = meta[e + 1];
        int c = nxt - prev;
        int t = (c + TM - 1) / TM;
        if (expert < 0 && bx < acc_t + t) {
            expert = e; row0 = prev + (bx - acc_t) * TM; rowmax = nxt - 1;
        }
        acc_t += t; prev = nxt;
    }
    if (expert < 0) return;

    const int col0 = blockIdx.y * TN;
    const u16* Wexp = Wt + (size_t)expert * N * K;

    const int lane = tid & 63;
    const int wid = tid >> 6;
    const int wm = (wid & 1) * 64;
    const int wn = (wid >> 1) * 64;
    const int l15 = lane & 15;
    const int lq = lane >> 4;

    // staging: slot idx in [0,1024) per matrix; row rl=idx>>3, chunk pos c=idx&7
    // holds global k-chunk (c ^ (rl&7)); LDS offset = idx*8 u16 (lane-contig).
    const u16* aptr[4]; const u16* bptr[4];
    int aoff[4], boff[4];
    #pragma unroll
    for (int s = 0; s < 4; s++) {
        int idx = tid + s * 256;
        int rl = idx >> 3, c = idx & 7;
        int kq = c ^ (rl & 7);
        int rg = row0 + rl; if (rg > rowmax) rg = rowmax;
        if (GATHER) rg = perm[rg];
        aptr[s] = A + (size_t)rg * K + kq * 8;
        bptr[s] = Wexp + (size_t)(col0 + rl) * K + kq * 8;
        aoff[s] = idx * 8;
        boff[s] = 8192 + idx * 8;
    }
    const int csw = l15 & 7;

    f32x4 acc[4][4];
    #pragma unroll
    for (int i = 0; i < 4; i++)
        #pragma unroll
        for (int j = 0; j < 4; j++) acc[i][j] = (f32x4){0.f, 0.f, 0.f, 0.f};

    // prologue: prefetch tile 0 into stage 0
    #pragma unroll
    for (int s = 0; s < 4; s++) {
        g2l16(aptr[s], &SM[aoff[s]]);
        g2l16(bptr[s], &SM[boff[s]]);
    }

    for (int t = 0; t < T; t++) {
        __syncthreads();    // drains this tile's DMA (prefetched last iter)
        const u16* As = &SM[(t & 1) * 16384];
        const u16* Bs = As + 8192;
        if (t + 1 < T) {    // prefetch next tile into other stage
            int base = ((t + 1) & 1) * 16384;
            int ko = (t + 1) * BK;
            #pragma unroll
            for (int s = 0; s < 4; s++) {
                g2l16(aptr[s] + ko, &SM[base + aoff[s]]);
                g2l16(bptr[s] + ko, &SM[base + boff[s]]);
            }
        }
        bf16x8 af[4][2], bf[4][2];
        #pragma unroll
        for (int h = 0; h < 2; h++) {
            const int ksw = (((h * 4 + lq) ^ csw)) * 8;
            #pragma unroll
            for (int i = 0; i < 4; i++)
                af[i][h] = *(const bf16x8*)&As[(wm + i * 16 + l15) * BK + ksw];
            #pragma unroll
            for (int j = 0; j < 4; j++)
                bf[j][h] = *(const bf16x8*)&Bs[(wn + j * 16 + l15) * BK + ksw];
        }
        #pragma unroll
        for (int h = 0; h < 2; h++)
            #pragma unroll
            for (int i = 0; i < 4; i++)
                #pragma unroll
                for (int j = 0; j < 4; j++)
                    acc[i][j] = __builtin_amdgcn_mfma_f32_16x16x32_bf16(
                        af[i][h], bf[j][h], acc[i][j], 0, 0, 0);
    }

    if (!FUSE3) {
        // epilogue: bias + ELU -> global bf16.  C/D: col=l15, row=lq*4+reg
        #pragma unroll
        for (int i = 0; i < 4; i++) {
            #pragma unroll
            for (int j = 0; j < 4; j++) {
                int col = col0 + wn + j * 16 + l15;
                float bv = bias[expert * N + col];
                #pragma unroll
                for (int r = 0; r < 4; r++) {
                    int grow = row0 + wm + i * 16 + lq * 4 + r;
                    if (grow <= rowmax) {
                        float v = acc[i][j][r] + bv;
                        v = (v > 0.f) ? v : (expf(v) - 1.f);
                        outb[(size_t)grow * N + col] = f2b(v);
                    }
                }
            }
        }
    } else {
        // ---- fused layer 3 (k-split over this block's 128 h-cols) ----
        __syncthreads();                 // all LDS reads of K-loop done
        u16* H = &SM[0];                 // [128][136] bf16, 34.8 KB
        #pragma unroll
        for (int i = 0; i < 4; i++) {
            #pragma unroll
            for (int j = 0; j < 4; j++) {
                int col = wn + j * 16 + l15;
                float bv = bias[expert * N + col0 + col];
                #pragma unroll
                for (int r = 0; r < 4; r++) {
                    float v = acc[i][j][r] + bv;
                    v = (v > 0.f) ? v : (expf(v) - 1.f);
                    H[(wm + i * 16 + lq * 4 + r) * 136 + col] = f2b(v);
                }
            }
        }
        __syncthreads();
        // wave split: row-half = wid&1, k-half = wid>>1 (64 k each, 2x32 iters)
        const int rh = (wid & 1) * 64;
        const int kb = (wid >> 1) * 64;
        f32x4 a3[4][3];
        #pragma unroll
        for (int i = 0; i < 4; i++)
            #pragma unroll
            for (int j = 0; j < 3; j++) a3[i][j] = (f32x4){0.f, 0.f, 0.f, 0.f};
        #pragma unroll
        for (int ki = 0; ki < 2; ki++) {
            int kl = kb + ki * 32;
            bf16x8 ha[4];
            #pragma unroll
            for (int i = 0; i < 4; i++)
                ha[i] = *(const bf16x8*)&H[(rh + i * 16 + l15) * 136 + kl + lq * 8];
            #pragma unroll
            for (int j = 0; j < 3; j++) {
                bf16x8 wb = *(const bf16x8*)
                    &Wt3[((size_t)expert * NP3 + j * 16 + l15) * H2n + col0 + kl + lq * 8];
                #pragma unroll
                for (int i = 0; i < 4; i++)
                    a3[i][j] = __builtin_amdgcn_mfma_f32_16x16x32_bf16(
                        ha[i], wb, a3[i][j], 0, 0, 0);
            }
        }
        #pragma unroll
        for (int j = 0; j < 3; j++) {
            int col = j * 16 + l15;
            if (col < Cn) {
                #pragma unroll
                for (int i = 0; i < 4; i++) {
                    #pragma unroll
                    for (int r = 0; r < 4; r++) {
                        int grow = row0 + rh + i * 16 + lq * 4 + r;
                        if (grow <= rowmax)
                            atomicAdd(&outf[(size_t)perm[grow] * Cn + col], a3[i][j][r]);
                    }
                }
            }
        }
    }
}

// ---------------------------------------------------------------------------
extern "C" void kernel_launch(void* const* d_in, const int* in_sizes, int n_in,
                              void* d_out, int out_size, void* d_ws, size_t ws_size,
                              hipStream_t stream)
{
    const float* xs = (const float*)d_in[0];
    const float* xp = (const float*)d_in[1];
    const float* W1 = (const float*)d_in[2];
    const float* b1 = (const float*)d_in[3];
    const float* W2 = (const float*)d_in[4];
    const float* b2 = (const float*)d_in[5];
    const float* W3 = (const float*)d_in[6];
    const float* b3 = (const float*)d_in[7];
    const int* label = (const int*)d_in[8];
    float* out = (float*)d_out;

    char* ws = (char*)d_ws;
    int* meta = (int*)ws;                                    // 64 B
    int* perm = (int*)(ws + 64);                             // 16 KB
    u16* Xb  = (u16*)(ws + (64 << 10));                      // 8 MB [4096][1024] (orig order)
    u16* W1t = (u16*)(ws + (64 << 10) + (8  << 20));         // 16 MB [8][1024][1024]
    u16* W2t = (u16*)(ws + (64 << 10) + (24 << 20));         // 8 MB  [8][512][1024]
    u16* h1b = (u16*)(ws + (64 << 10) + (32 << 20));         // 8 MB  [4096][1024] (sorted)
    u16* W3t = (u16*)(ws + (64 << 10) + (40 << 20));         // 393 KB [8][48][512]

    prep_kernel<<<PB_TOT, 256, 0, stream>>>(
        xs, xp, W1, W2, W3, b3, label, meta, perm, Xb, W1t, W2t, W3t, out);

    // L1: row tiles <= 4096/128 + 8 = 40; cols 1024/128 = 8
    mfma_gemm<K1n, H1n, true, false><<<dim3(40, 8), 256, 0, stream>>>(
        Xb, W1t, b1, meta, perm, h1b, nullptr, nullptr);

    // L2 (+fused L3): cols 512/128 = 4
    mfma_gemm<H1n, H2n, false, true><<<dim3(40, 4), 256, 0, stream>>>(
        h1b, W2t, b2, meta, perm, nullptr, W3t, out);
}